// Round 1
// baseline (944.738 us; speedup 1.0000x reference)
//
#include <hip/hip_runtime.h>
#include <hip/hip_bf16.h>

// Problem: LSTM (T=512, B=512, INPUT=300, HIDDEN=16) + MLP head, fp32.
// Phase 1: xg = x @ W_ih^T + (b_ih + b_hh)   [262144 x 300] @ [300 x 64] -> d_ws
// Phase 2: sequential scan over T with one wave per batch element + fused MLP head.

#define T_STEPS 512
#define BATCH   512
#define K_IN    300
#define NG      64   // 4*HIDDEN
#define HID     16

// ---------------------------------------------------------------------------
// GEMM: one thread per output row m (= t*B + b). 64 fp32 accumulators.
// x row streamed via float4 in 32-float chunks (one 128B line per lane per
// chunk -> full line utilization, no LDS needed). W_ih accessed with
// wave-uniform indices -> scalar loads broadcast through SGPRs.
// ---------------------------------------------------------------------------
__global__ __launch_bounds__(256) void xg_gemm(
    const float* __restrict__ x,      // [T*B][300]
    const float* __restrict__ W,      // [64][300]
    const float* __restrict__ b_ih,   // [64]
    const float* __restrict__ b_hh,   // [64]
    float* __restrict__ xg)           // [T*B][64]
{
    const int m = blockIdx.x * 256 + threadIdx.x;  // 0..262143
    const float* xr = x + (size_t)m * K_IN;

    float acc[NG];
#pragma unroll
    for (int g = 0; g < NG; ++g) acc[g] = 0.f;

    // main K loop: 9 chunks of 32
    for (int kc = 0; kc < 288; kc += 32) {
        union { float4 v4[8]; float f[32]; } xv;
#pragma unroll
        for (int j = 0; j < 8; ++j)
            xv.v4[j] = *(const float4*)(xr + kc + 4 * j);

#pragma unroll 2
        for (int g = 0; g < NG; ++g) {
            const float* wr = W + g * K_IN + kc;   // uniform across wave -> s_load
            float s0 = 0.f, s1 = 0.f;
#pragma unroll
            for (int k = 0; k < 32; k += 2) {
                s0 = fmaf(xv.f[k + 0], wr[k + 0], s0);
                s1 = fmaf(xv.f[k + 1], wr[k + 1], s1);
            }
            acc[g] += s0 + s1;
        }
    }
    // tail: 12 floats (kc = 288..299)
    {
        union { float4 v4[3]; float f[12]; } xv;
#pragma unroll
        for (int j = 0; j < 3; ++j)
            xv.v4[j] = *(const float4*)(xr + 288 + 4 * j);
#pragma unroll 2
        for (int g = 0; g < NG; ++g) {
            const float* wr = W + g * K_IN + 288;
            float s0 = 0.f, s1 = 0.f;
#pragma unroll
            for (int k = 0; k < 12; k += 2) {
                s0 = fmaf(xv.f[k + 0], wr[k + 0], s0);
                s1 = fmaf(xv.f[k + 1], wr[k + 1], s1);
            }
            acc[g] += s0 + s1;
        }
    }

    float* op = xg + (size_t)m * NG;
#pragma unroll
    for (int g = 0; g < NG; g += 4) {
        float4 v;
        v.x = acc[g + 0] + b_ih[g + 0] + b_hh[g + 0];
        v.y = acc[g + 1] + b_ih[g + 1] + b_hh[g + 1];
        v.z = acc[g + 2] + b_ih[g + 2] + b_hh[g + 2];
        v.w = acc[g + 3] + b_ih[g + 3] + b_hh[g + 3];
        *(float4*)(op + g) = v;
    }
}

// ---------------------------------------------------------------------------
// Scan: one wave (64 lanes) per batch element. Lane r owns gate r.
// h broadcast to the whole wave via v_readlane -> SGPRs (no LDS latency).
// c/h update computed redundantly in all 4 gate-groups (lane j = r&15).
// MLP head fused at the end.
// ---------------------------------------------------------------------------
__global__ __launch_bounds__(64) void lstm_scan(
    const float* __restrict__ xg,    // [T][B][64], biases already included
    const float* __restrict__ Whh,   // [64][16]
    const float* __restrict__ W1,    // [64][16]
    const float* __restrict__ b1,    // [64]
    const float* __restrict__ W2,    // [64]
    const float* __restrict__ b2,    // [1]
    float* __restrict__ out)         // [B]
{
    const int b = blockIdx.x;
    const int r = threadIdx.x;          // gate index 0..63
    const int jj = r & 15;              // hidden index this lane updates
    const bool isg = ((r >> 4) == 2);   // lanes 32..47 compute the g-gate (tanh)

    float whh[HID];
#pragma unroll
    for (int j = 0; j < HID; j += 4)
        *(float4*)&whh[j] = *(const float4*)(Whh + r * HID + j);

    float c = 0.f;
    float hs[HID];
#pragma unroll
    for (int j = 0; j < HID; ++j) hs[j] = 0.f;

    const float* xgb = xg + (size_t)b * NG + r;   // stride per t: B*NG
    float cur = xgb[0];
    float nxt = xgb[(size_t)BATCH * NG];

    for (int t = 0; t < T_STEPS; ++t) {
        float nn = 0.f;
        if (t + 2 < T_STEPS) nn = xgb[(size_t)(t + 2) * BATCH * NG];

        // gate pre-activation: xg + W_hh[r,:] . h   (h in SGPRs)
        float s0 = cur, s1 = 0.f;
#pragma unroll
        for (int j = 0; j < HID; j += 2) {
            s0 = fmaf(whh[j + 0], hs[j + 0], s0);
            s1 = fmaf(whh[j + 1], hs[j + 1], s1);
        }
        float gp = s0 + s1;

        // sigmoid for i/f/o lanes; tanh (=2*sigmoid(2x)-1) for g lanes
        float a   = isg ? 2.f * gp : gp;
        float sg  = 1.f / (1.f + __expf(-a));
        float act = isg ? fmaf(2.f, sg, -1.f) : sg;

        // gather i, f, g, o for hidden unit jj
        float iv = __shfl(act, jj,      64);
        float fv = __shfl(act, jj + 16, 64);
        float gv = __shfl(act, jj + 32, 64);
        float ov = __shfl(act, jj + 48, 64);

        c = fmaf(fv, c, iv * gv);
        float sc = 1.f / (1.f + __expf(-2.f * c));   // tanh(c)
        float h  = ov * fmaf(2.f, sc, -1.f);

        // broadcast h[0..15] (held by lanes 0..15) into SGPRs for next step
#pragma unroll
        for (int j = 0; j < HID; ++j)
            hs[j] = __int_as_float(__builtin_amdgcn_readlane(__float_as_int(h), j));

        cur = nxt;
        nxt = nn;
    }

    // ---- MLP head: z = relu(h @ W1^T + b1); out = 4*sigmoid(z @ W2^T + b2)
    float w1r[HID];
#pragma unroll
    for (int j = 0; j < HID; j += 4)
        *(float4*)&w1r[j] = *(const float4*)(W1 + r * HID + j);
    float z = b1[r];
#pragma unroll
    for (int j = 0; j < HID; ++j) z = fmaf(w1r[j], hs[j], z);
    z = fmaxf(z, 0.f);

    float y = z * W2[r];
#pragma unroll
    for (int off = 32; off; off >>= 1) y += __shfl_xor(y, off, 64);

    if (r == 0) out[b] = 4.f / (1.f + __expf(-(y + b2[0])));
}

extern "C" void kernel_launch(void* const* d_in, const int* in_sizes, int n_in,
                              void* d_out, int out_size, void* d_ws, size_t ws_size,
                              hipStream_t stream) {
    const float* x    = (const float*)d_in[0];
    const float* W_ih = (const float*)d_in[1];
    const float* W_hh = (const float*)d_in[2];
    const float* b_ih = (const float*)d_in[3];
    const float* b_hh = (const float*)d_in[4];
    const float* W1   = (const float*)d_in[5];
    const float* b1   = (const float*)d_in[6];
    const float* W2   = (const float*)d_in[7];
    const float* b2   = (const float*)d_in[8];
    float* out = (float*)d_out;
    float* xg  = (float*)d_ws;   // needs T*B*64*4 = 64 MiB

    xg_gemm<<<dim3(T_STEPS * BATCH / 256), dim3(256), 0, stream>>>(x, W_ih, b_ih, b_hh, xg);
    lstm_scan<<<dim3(BATCH), dim3(64), 0, stream>>>(xg, W_hh, W1, b1, W2, b2, out);
}